// Round 8
// baseline (306.978 us; speedup 1.0000x reference)
//
#include <hip/hip_runtime.h>
#include <hip/hip_fp16.h>
#include <math.h>

#define TT 4096
#define DD 1024
#define NH 16
#define HD 64

typedef __attribute__((ext_vector_type(8))) _Float16 half8v;
typedef __attribute__((ext_vector_type(4))) _Float16 half4v;
typedef __attribute__((ext_vector_type(4))) float f32x4;

#define GLDS16(g, l)                                                        \
    __builtin_amdgcn_global_load_lds(                                       \
        (const __attribute__((address_space(1))) void*)(g),                 \
        (__attribute__((address_space(3))) void*)(l), 16, 0, 0)

// ---------------- cast x -> fp16 ----------------
__global__ __launch_bounds__(256) void cast_x(const float* __restrict__ X,
                                              _Float16* __restrict__ Xh)
{
    const int i = (blockIdx.x * 256 + threadIdx.x) * 8;
    float4 a = *(const float4*)&X[i];
    float4 b = *(const float4*)&X[i + 4];
    half8v o = {(_Float16)a.x, (_Float16)a.y, (_Float16)a.z, (_Float16)a.w,
                (_Float16)b.x, (_Float16)b.y, (_Float16)b.z, (_Float16)b.w};
    *(half8v*)&Xh[i] = o;
}

// ---------------- transpose+cast W[K][N] fp32 -> WT[N][K] fp16 ----------------
__global__ __launch_bounds__(256) void transpose_cast(
    const float* __restrict__ W, _Float16* __restrict__ WT, int K, int N)
{
    __shared__ float tile[64][65];
    const int t = threadIdx.x;
    const int k0 = blockIdx.y * 64, n0 = blockIdx.x * 64;
    const int c = (t & 15) * 4, r = t >> 4;
#pragma unroll
    for (int i = 0; i < 4; i++) {
        float4 v = *(const float4*)&W[(size_t)(k0 + r + 16 * i) * N + n0 + c];
        tile[r + 16 * i][c + 0] = v.x;
        tile[r + 16 * i][c + 1] = v.y;
        tile[r + 16 * i][c + 2] = v.z;
        tile[r + 16 * i][c + 3] = v.w;
    }
    __syncthreads();
#pragma unroll
    for (int i = 0; i < 4; i++) {
        const int n = r + 16 * i;
        half4v o;
        o[0] = (_Float16)tile[c + 0][n];
        o[1] = (_Float16)tile[c + 1][n];
        o[2] = (_Float16)tile[c + 2][n];
        o[3] = (_Float16)tile[c + 3][n];
        *(half4v*)&WT[(size_t)(n0 + n) * K + k0 + c] = o;
    }
}

// ---------------- fp16 MFMA GEMM: C[M,N] = A[M,K] * Bt[N,K]^T ----------------
// MODE 0: write fp32 C0[M][N].
// MODE 1: qkv epilogue: Q,K fused RoPE (Q also *0.125*log2e) -> [h][t][hd];
//         V scattered into permuted Vp[h][kb][d][32], c' = 2*(t&15)+((t>>4)&1).
template <int MODE>
__global__ __launch_bounds__(256) void gemm_h(
    const _Float16* __restrict__ A, const _Float16* __restrict__ Bt,
    float* __restrict__ C0, _Float16* __restrict__ Q,
    _Float16* __restrict__ Kk, _Float16* __restrict__ V,
    int M, int N, int K)
{
    __shared__ _Float16 As[128 * 32];
    __shared__ _Float16 Bs[128 * 32];
    const int tid  = threadIdx.x;
    const int wave = tid >> 6;
    const int lane = tid & 63;
    const int quad = lane >> 4;
    const int n16  = lane & 15;
    const int n0 = blockIdx.x * 128;
    const int m0 = blockIdx.y * 128;
    const int wr = (wave & 1) * 64;
    const int wc = (wave >> 1) * 64;

    f32x4 acc[4][4];
#pragma unroll
    for (int i = 0; i < 4; i++)
#pragma unroll
        for (int j = 0; j < 4; j++) acc[i][j] = (f32x4){0.f, 0.f, 0.f, 0.f};

    const int srow = tid >> 2;
    const int scol = (tid & 3) * 8;
    const _Float16* Ag = A + (size_t)(m0 + srow) * K + scol;
    const _Float16* Bg = Bt + (size_t)(n0 + srow) * K + scol;
    _Float16* AsW = As + (size_t)wave * 512;
    _Float16* BsW = Bs + (size_t)wave * 512;

    for (int k0 = 0; k0 < K; k0 += 32) {
        __syncthreads();
        GLDS16(Ag + k0, AsW);
        GLDS16(Ag + (size_t)64 * K + k0, AsW + 2048);
        GLDS16(Bg + k0, BsW);
        GLDS16(Bg + (size_t)64 * K + k0, BsW + 2048);
        __syncthreads();

        half8v aF[4], bF[4];
#pragma unroll
        for (int i = 0; i < 4; i++)
            aF[i] = *(const half8v*)&As[(size_t)(wr + i * 16 + n16) * 32 + quad * 8];
#pragma unroll
        for (int j = 0; j < 4; j++)
            bF[j] = *(const half8v*)&Bs[(size_t)(wc + j * 16 + n16) * 32 + quad * 8];
#pragma unroll
        for (int i = 0; i < 4; i++)
#pragma unroll
            for (int j = 0; j < 4; j++)
                acc[i][j] = __builtin_amdgcn_mfma_f32_16x16x32_f16(
                    aF[i], bF[j], acc[i][j], 0, 0, 0);
    }

    if (MODE == 0) {
#pragma unroll
        for (int i = 0; i < 4; i++)
#pragma unroll
            for (int j = 0; j < 4; j++)
#pragma unroll
                for (int r = 0; r < 4; r++) {
                    const int m = m0 + wr + i * 16 + quad * 4 + r;
                    const int n = n0 + wc + j * 16 + n16;
                    C0[(size_t)m * N + n] = acc[i][j][r];
                }
    } else {
        const int ncol0 = n0 + wc;                 // wave spans one head
        const int which = ncol0 >> 10;             // 0:q 1:k 2:v
        const int h = (ncol0 & 1023) >> 6;
        if (which < 2) {
            _Float16* dst = (which == 0) ? Q : Kk;
            const float sc = (which == 0) ? 0.125f * 1.44269504f : 1.0f;
            const float K2 = 0.4152410118609203f;  // log2(10000)/32
#pragma unroll
            for (int jlo = 0; jlo < 2; jlo++) {
                const int d = jlo * 16 + n16;
                const float invf = exp2f(-(float)d * K2);
#pragma unroll
                for (int i = 0; i < 4; i++) {
#pragma unroll
                    for (int r = 0; r < 4; r++) {
                        const int t = m0 + wr + i * 16 + quad * 4 + r;
                        const float f = (float)t * invf;
                        float sn, cs;
                        __sincosf(f, &sn, &cs);
                        const float lo = acc[i][jlo][r];
                        const float hi = acc[i][jlo + 2][r];
                        const size_t off = ((size_t)h * TT + t) * HD + d;
                        dst[off]      = (_Float16)((lo * cs - hi * sn) * sc);
                        dst[off + 32] = (_Float16)((hi * cs + lo * sn) * sc);
                    }
                }
            }
        } else {
#pragma unroll
            for (int i = 0; i < 4; i++)
#pragma unroll
                for (int j = 0; j < 4; j++)
#pragma unroll
                    for (int r = 0; r < 4; r++) {
                        const int t = m0 + wr + i * 16 + quad * 4 + r;
                        const int d = j * 16 + n16;
                        const int cp = 2 * (t & 15) + ((t >> 4) & 1);
                        V[(((size_t)h * (TT / 32) + (t >> 5)) * 64 + d) * 32 + cp] =
                            (_Float16)acc[i][j][r];
                    }
        }
    }
}

// ---------------- zero O/L accumulators ----------------
__global__ __launch_bounds__(256) void zero_acc(float4* __restrict__ O4,
                                                float4* __restrict__ L4)
{
    const int i = blockIdx.x * 256 + threadIdx.x;   // 524288
    const float4 z = {0.f, 0.f, 0.f, 0.f};
    O4[i] = z;
    if (i < 16384) L4[i] = z;
}

// ---------------- split-K flash attention: 64-key tiles, dbuf, swizzled -----
// grid (slice=8, qt=32, h=16); block = 4 waves x 32 q-rows = 128 rows.
// One barrier per tile; GLDS(it+1) issued right after it, drained next iter.
// 16B chunks XOR-swizzled: slot = ks ^ ((row>>1)&3) -> 2-way max on frag reads.
__global__ __launch_bounds__(256) void attn_kernel(
    const _Float16* __restrict__ Qh, const _Float16* __restrict__ Kh,
    const _Float16* __restrict__ Vp, _Float16* __restrict__ Oacc,
    float* __restrict__ Lacc)
{
    __shared__ _Float16 Ks[2][2][64][32];   // [buf][kc][key][32]  16 KB
    __shared__ _Float16 Vs[2][2][64][32];   // [buf][kb][d][32]    16 KB
    __shared__ _Float16 Ps[4][32][40];      // per-wave P          10 KB

    const int tid  = threadIdx.x;
    const int wave = tid >> 6;
    const int lane = tid & 63;
    const int quad = lane >> 4;
    const int n16  = lane & 15;
    const int h  = blockIdx.z;
    const int qt = 31 - blockIdx.y;          // longest first
    const int s  = blockIdx.x;
    const int nT = 2 * qt + 2;               // 64-key tiles
    const int nS = (qt + 4) >> 2;            // ceil((qt+1)/4)
    if (s >= nS) return;
    const int t_beg = s * nT / nS;
    const int t_end = (s + 1) * nT / nS;

    const int q0 = qt * 128;
    const int rowbase = q0 + wave * 32;

    const _Float16* Qg = Qh + (size_t)h * TT * HD;
    const _Float16* Kg = Kh + (size_t)h * TT * HD;
    const _Float16* Vg = Vp + (size_t)h * (TT / 32) * 2048;

    half8v aQ[2][2];
#pragma unroll
    for (int g = 0; g < 2; g++) {
        const int row = rowbase + g * 16 + n16;
#pragma unroll
        for (int c = 0; c < 2; c++)
            aQ[g][c] = *(const half8v*)(Qg + (size_t)row * HD + c * 32 + quad * 8);
    }

    f32x4 O[2][4], Ol[2];
#pragma unroll
    for (int g = 0; g < 2; g++) {
#pragma unroll
        for (int d = 0; d < 4; d++) O[g][d] = (f32x4){0.f, 0.f, 0.f, 0.f};
        Ol[g] = (f32x4){0.f, 0.f, 0.f, 0.f};
    }
    const half8v vOnes = {(_Float16)1, (_Float16)1, (_Float16)1, (_Float16)1,
                          (_Float16)1, (_Float16)1, (_Float16)1, (_Float16)1};

    // staging source addresses (64B rows, XOR-swizzled 16B chunks)
    const int srow = tid >> 2;               // 0..63
    const int schk = tid & 3;
    const int sswz = schk ^ ((srow >> 1) & 3);
    const _Float16* kSrc = Kg + (size_t)srow * HD + sswz * 8;   // + j0*HD + kc*32
    const _Float16* vSrc = Vg + (size_t)srow * 32 + sswz * 8;   // + (2it+vc)*2048
    _Float16* ksB0 = &Ks[0][0][0][0] + (size_t)wave * 512;
    _Float16* vsB0 = &Vs[0][0][0][0] + (size_t)wave * 512;

    // reader slot offset (halves): chunk quad lives at quad ^ ((n16>>1)&3)
    const int slot = (quad ^ ((n16 >> 1) & 3)) * 8;

#define STAGE(buf, it)                                                        \
    do {                                                                      \
        const size_t ko = (size_t)(it) * 64 * HD;                             \
        GLDS16(kSrc + ko,      ksB0 + (size_t)(buf) * 4096);                  \
        GLDS16(kSrc + ko + 32, ksB0 + (size_t)(buf) * 4096 + 2048);           \
        const size_t vo = (size_t)(it) * 4096;                                \
        GLDS16(vSrc + vo,        vsB0 + (size_t)(buf) * 4096);                \
        GLDS16(vSrc + vo + 2048, vsB0 + (size_t)(buf) * 4096 + 2048);         \
    } while (0)

    STAGE(t_beg & 1, t_beg);

    for (int it = t_beg; it < t_end; ++it) {
        const int j0 = it * 64;
        __syncthreads();                       // drains GLDS(it) (issued last iter)
        if (it + 1 < t_end) STAGE((it + 1) & 1, it + 1);
        const int b = it & 1;

        if (j0 > rowbase + 31) continue;       // fully masked for this wave

        // ---- QK: 4 subtiles of 16 keys ----
        half8v bK[2][4];
#pragma unroll
        for (int c = 0; c < 2; c++)
#pragma unroll
            for (int st = 0; st < 4; st++)
                bK[c][st] = *(const half8v*)&Ks[b][c][st * 16 + n16][slot];

        f32x4 S[2][4];
#pragma unroll
        for (int g = 0; g < 2; g++)
#pragma unroll
            for (int st = 0; st < 4; st++) {
                S[g][st] = (f32x4){0.f, 0.f, 0.f, 0.f};
#pragma unroll
                for (int c = 0; c < 2; c++)
                    S[g][st] = __builtin_amdgcn_mfma_f32_16x16x32_f16(
                        aQ[g][c], bK[c][st], S[g][st], 0, 0, 0);
            }

        // ---- two 32-key halves: softmax -> Ps -> PV ----
#pragma unroll
        for (int hv = 0; hv < 2; hv++) {
            const int jh = j0 + hv * 32;
            if (jh > rowbase + 31) continue;
            const bool needMask = (jh + 31 > rowbase);

#pragma unroll
            for (int g = 0; g < 2; g++)
#pragma unroll
                for (int r = 0; r < 4; r++) {
                    const int row = rowbase + g * 16 + quad * 4 + r;
                    float x0 = S[g][2 * hv][r];
                    float x1 = S[g][2 * hv + 1][r];
                    if (needMask) {
                        x0 = (jh + n16      <= row) ? x0 : -1e30f;
                        x1 = (jh + 16 + n16 <= row) ? x1 : -1e30f;
                    }
                    const float p0 = __builtin_amdgcn_exp2f(x0);
                    const float p1 = __builtin_amdgcn_exp2f(x1);
                    *(__half2*)&Ps[wave][g * 16 + quad * 4 + r][2 * n16] =
                        __floats2half2_rn(p0, p1);
                }

            half8v bV[4];
#pragma unroll
            for (int d = 0; d < 4; d++)
                bV[d] = *(const half8v*)&Vs[b][hv][d * 16 + n16][slot];
#pragma unroll
            for (int g = 0; g < 2; g++) {
                half8v aP = *(const half8v*)&Ps[wave][g * 16 + n16][quad * 8];
#pragma unroll
                for (int d = 0; d < 4; d++)
                    O[g][d] = __builtin_amdgcn_mfma_f32_16x16x32_f16(
                        aP, bV[d], O[g][d], 0, 0, 0);
                Ol[g] = __builtin_amdgcn_mfma_f32_16x16x32_f16(
                    aP, vOnes, Ol[g], 0, 0, 0);
            }
        }
    }

    // epilogue: atomic partial accumulate (Ol holds per-row l)
#pragma unroll
    for (int g = 0; g < 2; g++)
#pragma unroll
        for (int r = 0; r < 4; r++) {
            const int row = rowbase + g * 16 + quad * 4 + r;
            if (n16 == 0)
                unsafeAtomicAdd(&Lacc[h * TT + row], Ol[g][r]);
#pragma unroll
            for (int d = 0; d < 4; d++) {
                float v = O[g][d][r];
                float vn = __shfl_xor(v, 1);
                if ((lane & 1) == 0) {
                    __half2* dst = (__half2*)(Oacc +
                        ((size_t)h * TT + row) * HD + d * 16 + n16);
                    unsafeAtomicAdd(dst, __floats2half2_rn(v, vn));
                }
            }
        }
}

// ---------------- finalize: Y[t][h*64+d] = Oacc/Lacc (fp16) ----------------
__global__ __launch_bounds__(256) void finalize(
    const _Float16* __restrict__ Oacc, const float* __restrict__ Lacc,
    _Float16* __restrict__ Y)
{
    const int gid = blockIdx.x * 256 + threadIdx.x;   // 524288
    const int h = gid >> 15;
    const int rem = gid & 32767;
    const int t = rem >> 3;
    const int c = rem & 7;
    const float inv = 1.0f / Lacc[h * TT + t];
    half8v o = *(const half8v*)(Oacc + ((size_t)h * TT + t) * HD + c * 8);
    half8v y;
#pragma unroll
    for (int e = 0; e < 8; e++) y[e] = (_Float16)((float)o[e] * inv);
    *(half8v*)(Y + (size_t)t * DD + h * HD + c * 8) = y;
}

extern "C" void kernel_launch(void* const* d_in, const int* in_sizes, int n_in,
                              void* d_out, int out_size, void* d_ws, size_t ws_size,
                              hipStream_t stream)
{
    const float* x      = (const float*)d_in[0];
    const float* w_qkv  = (const float*)d_in[1];
    const float* w_proj = (const float*)d_in[2];
    float* out = (float*)d_out;

    char* ws = (char*)d_ws;
    const size_t MB = 1u << 20;
    _Float16* xh   = (_Float16*)(ws);               //  8 MB
    _Float16* WqT  = (_Float16*)(ws + 8 * MB);      //  6 MB
    _Float16* WpT  = (_Float16*)(ws + 14 * MB);     //  2 MB
    _Float16* Qh   = (_Float16*)(ws + 16 * MB);     //  8 MB
    _Float16* Kh   = (_Float16*)(ws + 24 * MB);     //  8 MB
    _Float16* Vp   = (_Float16*)(ws + 32 * MB);     //  8 MB (permuted)
    _Float16* Yh   = (_Float16*)(ws + 40 * MB);     //  8 MB
    _Float16* Oacc = (_Float16*)(ws + 48 * MB);     //  8.4 MB
    float*    Lacc = (float*)(ws + 57 * MB);        //  0.26 MB

    dim3 blk(256);

    cast_x<<<(TT * DD) / (256 * 8), blk, 0, stream>>>(x, xh);
    transpose_cast<<<dim3(3072 / 64, DD / 64), blk, 0, stream>>>(w_qkv, WqT, DD, 3 * DD);
    transpose_cast<<<dim3(DD / 64, DD / 64), blk, 0, stream>>>(w_proj, WpT, DD, DD);

    gemm_h<1><<<dim3(3072 / 128, TT / 128), blk, 0, stream>>>(
        xh, WqT, nullptr, Qh, Kh, Vp, TT, 3 * DD, DD);

    zero_acc<<<2048, blk, 0, stream>>>((float4*)Oacc, (float4*)Lacc);

    attn_kernel<<<dim3(8, 32, NH), blk, 0, stream>>>(Qh, Kh, Vp, Oacc, Lacc);

    finalize<<<2048, blk, 0, stream>>>(Oacc, Lacc, Yh);

    gemm_h<0><<<dim3(DD / 128, TT / 128), blk, 0, stream>>>(
        Yh, WpT, out, nullptr, nullptr, nullptr, TT, DD, DD);
}

// Round 9
// 263.613 us; speedup vs baseline: 1.1645x; 1.1645x over previous
//
#include <hip/hip_runtime.h>
#include <hip/hip_fp16.h>
#include <math.h>

#define TT 4096
#define DD 1024
#define NH 16
#define HD 64

typedef __attribute__((ext_vector_type(8))) _Float16 half8v;
typedef __attribute__((ext_vector_type(4))) _Float16 half4v;
typedef __attribute__((ext_vector_type(4))) float f32x4;

#define GLDS16(g, l)                                                        \
    __builtin_amdgcn_global_load_lds(                                       \
        (const __attribute__((address_space(1))) void*)(g),                 \
        (__attribute__((address_space(3))) void*)(l), 16, 0, 0)

// ---------------- cast x -> fp16, and zero O/L accumulators ----------------
__global__ __launch_bounds__(256) void cast_x_zero(
    const float* __restrict__ X, _Float16* __restrict__ Xh,
    float4* __restrict__ O4, float4* __restrict__ L4)
{
    const int t = blockIdx.x * 256 + threadIdx.x;    // 524288 threads
    const int i = t * 8;
    float4 a = *(const float4*)&X[i];
    float4 b = *(const float4*)&X[i + 4];
    half8v o = {(_Float16)a.x, (_Float16)a.y, (_Float16)a.z, (_Float16)a.w,
                (_Float16)b.x, (_Float16)b.y, (_Float16)b.z, (_Float16)b.w};
    *(half8v*)&Xh[i] = o;
    const float4 z = {0.f, 0.f, 0.f, 0.f};
    O4[t] = z;
    if (t < 16384) L4[t] = z;
}

// ---------------- transpose+cast W[K][N] fp32 -> WT[N][K] fp16 ----------------
__global__ __launch_bounds__(256) void transpose_cast(
    const float* __restrict__ W, _Float16* __restrict__ WT, int K, int N)
{
    __shared__ float tile[64][65];
    const int t = threadIdx.x;
    const int k0 = blockIdx.y * 64, n0 = blockIdx.x * 64;
    const int c = (t & 15) * 4, r = t >> 4;
#pragma unroll
    for (int i = 0; i < 4; i++) {
        float4 v = *(const float4*)&W[(size_t)(k0 + r + 16 * i) * N + n0 + c];
        tile[r + 16 * i][c + 0] = v.x;
        tile[r + 16 * i][c + 1] = v.y;
        tile[r + 16 * i][c + 2] = v.z;
        tile[r + 16 * i][c + 3] = v.w;
    }
    __syncthreads();
#pragma unroll
    for (int i = 0; i < 4; i++) {
        const int n = r + 16 * i;
        half4v o;
        o[0] = (_Float16)tile[c + 0][n];
        o[1] = (_Float16)tile[c + 1][n];
        o[2] = (_Float16)tile[c + 2][n];
        o[3] = (_Float16)tile[c + 3][n];
        *(half4v*)&WT[(size_t)(n0 + n) * K + k0 + c] = o;
    }
}

// ---------------- fp16 MFMA GEMM: C[M,N] = A[M,K] * Bt[N,K]^T ----------------
// Staging XOR-swizzled (slot = chunk ^ ((row>>1)&3)) -> 2-way max on frag reads.
// MODE 0: write fp32 C0[M][N].
// MODE 1: qkv epilogue: Q,K fused RoPE (Q also *0.125*log2e) -> [h][t][hd];
//         V -> permuted Vp[h][kb][d][32] via vectorized half8 stores.
template <int MODE>
__global__ __launch_bounds__(256) void gemm_h(
    const _Float16* __restrict__ A, const _Float16* __restrict__ Bt,
    float* __restrict__ C0, _Float16* __restrict__ Q,
    _Float16* __restrict__ Kk, _Float16* __restrict__ V,
    int M, int N, int K)
{
    __shared__ _Float16 As[128 * 32];
    __shared__ _Float16 Bs[128 * 32];
    const int tid  = threadIdx.x;
    const int wave = tid >> 6;
    const int lane = tid & 63;
    const int quad = lane >> 4;
    const int n16  = lane & 15;
    const int n0 = blockIdx.x * 128;
    const int m0 = blockIdx.y * 128;
    const int wr = (wave & 1) * 64;
    const int wc = (wave >> 1) * 64;

    f32x4 acc[4][4];
#pragma unroll
    for (int i = 0; i < 4; i++)
#pragma unroll
        for (int j = 0; j < 4; j++) acc[i][j] = (f32x4){0.f, 0.f, 0.f, 0.f};

    const int srow = tid >> 2;
    const int schk = tid & 3;
    const int sswz = (schk ^ ((srow >> 1) & 3)) * 8;
    const _Float16* Ag = A + (size_t)(m0 + srow) * K + sswz;
    const _Float16* Bg = Bt + (size_t)(n0 + srow) * K + sswz;
    _Float16* AsW = As + (size_t)wave * 512;
    _Float16* BsW = Bs + (size_t)wave * 512;
    const int slot = (quad ^ ((n16 >> 1) & 3)) * 8;   // reader slot

    for (int k0 = 0; k0 < K; k0 += 32) {
        __syncthreads();
        GLDS16(Ag + k0, AsW);
        GLDS16(Ag + (size_t)64 * K + k0, AsW + 2048);
        GLDS16(Bg + k0, BsW);
        GLDS16(Bg + (size_t)64 * K + k0, BsW + 2048);
        __syncthreads();

        half8v aF[4], bF[4];
#pragma unroll
        for (int i = 0; i < 4; i++)
            aF[i] = *(const half8v*)&As[(size_t)(wr + i * 16 + n16) * 32 + slot];
#pragma unroll
        for (int j = 0; j < 4; j++)
            bF[j] = *(const half8v*)&Bs[(size_t)(wc + j * 16 + n16) * 32 + slot];
#pragma unroll
        for (int i = 0; i < 4; i++)
#pragma unroll
            for (int j = 0; j < 4; j++)
                acc[i][j] = __builtin_amdgcn_mfma_f32_16x16x32_f16(
                    aF[i], bF[j], acc[i][j], 0, 0, 0);
    }

    if (MODE == 0) {
#pragma unroll
        for (int i = 0; i < 4; i++)
#pragma unroll
            for (int j = 0; j < 4; j++)
#pragma unroll
                for (int r = 0; r < 4; r++) {
                    const int m = m0 + wr + i * 16 + quad * 4 + r;
                    const int n = n0 + wc + j * 16 + n16;
                    C0[(size_t)m * N + n] = acc[i][j][r];
                }
    } else {
        const int ncol0 = n0 + wc;                 // wave spans one head
        const int which = ncol0 >> 10;             // 0:q 1:k 2:v
        const int h = (ncol0 & 1023) >> 6;
        if (which < 2) {
            _Float16* dst = (which == 0) ? Q : Kk;
            const float sc = (which == 0) ? 0.125f * 1.44269504f : 1.0f;
            const float K2 = 0.4152410118609203f;  // log2(10000)/32
#pragma unroll
            for (int jlo = 0; jlo < 2; jlo++) {
                const int d = jlo * 16 + n16;
                const float invf = exp2f(-(float)d * K2);
#pragma unroll
                for (int i = 0; i < 4; i++) {
#pragma unroll
                    for (int r = 0; r < 4; r++) {
                        const int t = m0 + wr + i * 16 + quad * 4 + r;
                        const float f = (float)t * invf;
                        float sn, cs;
                        __sincosf(f, &sn, &cs);
                        const float lo = acc[i][jlo][r];
                        const float hi = acc[i][jlo + 2][r];
                        const size_t off = ((size_t)h * TT + t) * HD + d;
                        dst[off]      = (_Float16)((lo * cs - hi * sn) * sc);
                        dst[off + 32] = (_Float16)((hi * cs + lo * sn) * sc);
                    }
                }
            }
        } else {
            // Vectorized V scatter: lane's (i-pair, j) accs are exactly the
            // 16B chunk Vp[h][kbg][d=j*16+n16][quad*8 .. +8) under the cp
            // permutation c' = 2*(t&15)+((t>>4)&1).
#pragma unroll
            for (int kb2 = 0; kb2 < 2; kb2++) {
                const int kbg = ((m0 + wr) >> 5) + kb2;
#pragma unroll
                for (int j = 0; j < 4; j++) {
                    const int d = j * 16 + n16;
                    half8v o;
#pragma unroll
                    for (int r = 0; r < 4; r++) {
                        o[2 * r]     = (_Float16)acc[2 * kb2][j][r];
                        o[2 * r + 1] = (_Float16)acc[2 * kb2 + 1][j][r];
                    }
                    *(half8v*)(V + (((size_t)h * (TT / 32) + kbg) * 64 + d) * 32
                               + quad * 8) = o;
                }
            }
        }
    }
}

// ---------------- split-K flash attention (no-max exact softmax) -------------
// grid (slice=4, qt=32, h=16); block = 4 waves x 32 q-rows = 128 rows.
// 32-key tiles, single buffer (18KB LDS), XOR-swizzled staging, ones-MFMA l.
__global__ __launch_bounds__(256) void attn_kernel(
    const _Float16* __restrict__ Qh, const _Float16* __restrict__ Kh,
    const _Float16* __restrict__ Vp, _Float16* __restrict__ Oacc,
    float* __restrict__ Lacc)
{
    __shared__ _Float16 Ks[2][32][32];   // [kchunk][key][32]      4 KB
    __shared__ _Float16 Vs[64][32];      // [d][key-perm]          4 KB
    __shared__ _Float16 Ps[4][32][40];   // per-wave [row][c'] pad 10 KB

    const int tid  = threadIdx.x;
    const int wave = tid >> 6;
    const int lane = tid & 63;
    const int quad = lane >> 4;
    const int n16  = lane & 15;
    const int h  = blockIdx.z;
    const int qt = 31 - blockIdx.y;          // longest first
    const int s  = blockIdx.x;
    const int nT = 4 * qt + 4;
    const int nS = (qt + 8) >> 3;            // ceil((qt+1)/8)
    if (s >= nS) return;
    const int t_beg = s * nT / nS;
    const int t_end = (s + 1) * nT / nS;

    const int q0 = qt * 128;
    const int rowbase = q0 + wave * 32;

    const _Float16* Qg = Qh + (size_t)h * TT * HD;
    const _Float16* Kg = Kh + (size_t)h * TT * HD;
    const _Float16* Vg = Vp + (size_t)h * (TT / 32) * 2048;

    half8v aQ[2][2];
#pragma unroll
    for (int g = 0; g < 2; g++) {
        const int row = rowbase + g * 16 + n16;
#pragma unroll
        for (int c = 0; c < 2; c++)
            aQ[g][c] = *(const half8v*)(Qg + (size_t)row * HD + c * 32 + quad * 8);
    }

    f32x4 O[2][4], Ol[2];
#pragma unroll
    for (int g = 0; g < 2; g++) {
#pragma unroll
        for (int d = 0; d < 4; d++) O[g][d] = (f32x4){0.f, 0.f, 0.f, 0.f};
        Ol[g] = (f32x4){0.f, 0.f, 0.f, 0.f};
    }
    const half8v vOnes = {(_Float16)1, (_Float16)1, (_Float16)1, (_Float16)1,
                          (_Float16)1, (_Float16)1, (_Float16)1, (_Float16)1};

    // staging: XOR-swizzled 16B chunks (slot = chunk ^ ((row>>1)&3))
    const int kc = tid >> 7, kj = (tid >> 2) & 31, ks = tid & 3;
    const _Float16* kSrc = Kg + (size_t)kj * HD + kc * 32
                           + (size_t)(ks ^ ((kj >> 1) & 3)) * 8;
    const int vd = tid >> 2, vs = tid & 3;
    const _Float16* vSrc = Vg + (size_t)vd * 32
                           + (size_t)(vs ^ ((vd >> 1) & 3)) * 8;
    _Float16* ksBase = &Ks[0][0][0] + (size_t)wave * 512;
    _Float16* vsBase = &Vs[0][0] + (size_t)wave * 512;
    const int slot = (quad ^ ((n16 >> 1) & 3)) * 8;   // reader slot

    for (int it = t_beg; it < t_end; ++it) {
        const int j0 = it * 32;
        __syncthreads();
        GLDS16(kSrc + (size_t)j0 * HD, ksBase);
        GLDS16(vSrc + (size_t)it * 2048, vsBase);
        __syncthreads();

        if (j0 <= rowbase + 31) {
            const bool needMask = (j0 + 31 > rowbase);

            f32x4 S[2][2];
#pragma unroll
            for (int g = 0; g < 2; g++)
#pragma unroll
                for (int st = 0; st < 2; st++) {
                    S[g][st] = (f32x4){0.f, 0.f, 0.f, 0.f};
#pragma unroll
                    for (int c = 0; c < 2; c++) {
                        half8v bK = *(const half8v*)&Ks[c][st * 16 + n16][slot];
                        S[g][st] = __builtin_amdgcn_mfma_f32_16x16x32_f16(
                            aQ[g][c], bK, S[g][st], 0, 0, 0);
                    }
                }

#pragma unroll
            for (int g = 0; g < 2; g++)
#pragma unroll
                for (int r = 0; r < 4; r++) {
                    const int row = rowbase + g * 16 + quad * 4 + r;
                    float x0 = S[g][0][r];
                    float x1 = S[g][1][r];
                    if (needMask) {
                        x0 = (j0 + n16      <= row) ? x0 : -1e30f;
                        x1 = (j0 + 16 + n16 <= row) ? x1 : -1e30f;
                    }
                    const float p0 = __builtin_amdgcn_exp2f(x0);
                    const float p1 = __builtin_amdgcn_exp2f(x1);
                    *(__half2*)&Ps[wave][g * 16 + quad * 4 + r][2 * n16] =
                        __floats2half2_rn(p0, p1);
                }

            half8v bV[4];
#pragma unroll
            for (int d = 0; d < 4; d++)
                bV[d] = *(const half8v*)&Vs[d * 16 + n16][slot];
#pragma unroll
            for (int g = 0; g < 2; g++) {
                half8v aP = *(const half8v*)&Ps[wave][g * 16 + n16][quad * 8];
#pragma unroll
                for (int d = 0; d < 4; d++)
                    O[g][d] = __builtin_amdgcn_mfma_f32_16x16x32_f16(
                        aP, bV[d], O[g][d], 0, 0, 0);
                Ol[g] = __builtin_amdgcn_mfma_f32_16x16x32_f16(
                    aP, vOnes, Ol[g], 0, 0, 0);
            }
        }
    }

    // epilogue: atomic partial accumulate (Ol holds per-row l)
#pragma unroll
    for (int g = 0; g < 2; g++)
#pragma unroll
        for (int r = 0; r < 4; r++) {
            const int row = rowbase + g * 16 + quad * 4 + r;
            if (n16 == 0)
                unsafeAtomicAdd(&Lacc[h * TT + row], Ol[g][r]);
#pragma unroll
            for (int d = 0; d < 4; d++) {
                float v = O[g][d][r];
                float vn = __shfl_xor(v, 1);
                if ((lane & 1) == 0) {
                    __half2* dst = (__half2*)(Oacc +
                        ((size_t)h * TT + row) * HD + d * 16 + n16);
                    unsafeAtomicAdd(dst, __floats2half2_rn(v, vn));
                }
            }
        }
}

// ---------------- finalize: Y[t][h*64+d] = Oacc/Lacc (fp16) ----------------
__global__ __launch_bounds__(256) void finalize(
    const _Float16* __restrict__ Oacc, const float* __restrict__ Lacc,
    _Float16* __restrict__ Y)
{
    const int gid = blockIdx.x * 256 + threadIdx.x;   // 524288
    const int h = gid >> 15;
    const int rem = gid & 32767;
    const int t = rem >> 3;
    const int c = rem & 7;
    const float inv = 1.0f / Lacc[h * TT + t];
    half8v o = *(const half8v*)(Oacc + ((size_t)h * TT + t) * HD + c * 8);
    half8v y;
#pragma unroll
    for (int e = 0; e < 8; e++) y[e] = (_Float16)((float)o[e] * inv);
    *(half8v*)(Y + (size_t)t * DD + h * HD + c * 8) = y;
}

extern "C" void kernel_launch(void* const* d_in, const int* in_sizes, int n_in,
                              void* d_out, int out_size, void* d_ws, size_t ws_size,
                              hipStream_t stream)
{
    const float* x      = (const float*)d_in[0];
    const float* w_qkv  = (const float*)d_in[1];
    const float* w_proj = (const float*)d_in[2];
    float* out = (float*)d_out;

    char* ws = (char*)d_ws;
    const size_t MB = 1u << 20;
    _Float16* xh   = (_Float16*)(ws);               //  8 MB
    _Float16* WqT  = (_Float16*)(ws + 8 * MB);      //  6 MB
    _Float16* WpT  = (_Float16*)(ws + 14 * MB);     //  2 MB
    _Float16* Qh   = (_Float16*)(ws + 16 * MB);     //  8 MB
    _Float16* Kh   = (_Float16*)(ws + 24 * MB);     //  8 MB
    _Float16* Vp   = (_Float16*)(ws + 32 * MB);     //  8 MB (permuted)
    _Float16* Yh   = (_Float16*)(ws + 40 * MB);     //  8 MB
    _Float16* Oacc = (_Float16*)(ws + 48 * MB);     //  8.4 MB
    float*    Lacc = (float*)(ws + 57 * MB);        //  0.26 MB

    dim3 blk(256);

    cast_x_zero<<<2048, blk, 0, stream>>>(x, xh, (float4*)Oacc, (float4*)Lacc);
    transpose_cast<<<dim3(3072 / 64, DD / 64), blk, 0, stream>>>(w_qkv, WqT, DD, 3 * DD);
    transpose_cast<<<dim3(DD / 64, DD / 64), blk, 0, stream>>>(w_proj, WpT, DD, DD);

    gemm_h<1><<<dim3(3072 / 128, TT / 128), blk, 0, stream>>>(
        xh, WqT, nullptr, Qh, Kh, Vp, TT, 3 * DD, DD);

    attn_kernel<<<dim3(4, 32, NH), blk, 0, stream>>>(Qh, Kh, Vp, Oacc, Lacc);

    finalize<<<2048, blk, 0, stream>>>(Oacc, Lacc, Yh);

    gemm_h<0><<<dim3(DD / 128, TT / 128), blk, 0, stream>>>(
        Yh, WpT, out, nullptr, nullptr, nullptr, TT, DD, DD);
}